// Round 6
// baseline (488.448 us; speedup 1.0000x reference)
//
#include <hip/hip_runtime.h>

#define NN 100000
#define NE 1200000
#define NG 2000
#define IND 36
#define HIDD 64
#define BN_EPS 1e-5f

// ---------------- CSR build ----------------

__global__ void k_indeg(const int* __restrict__ dst, int* __restrict__ indeg) {
    int e = blockIdx.x * 256 + threadIdx.x;
    if (e < NE) atomicAdd(&indeg[dst[e]], 1);
}

// block-sum for scan + dinv (folded in: reads indeg anyway)
__global__ void k_scan1(const int* __restrict__ indeg, int* __restrict__ bsum,
                        float* __restrict__ dinv) {
    __shared__ int sh[256];
    int i = blockIdx.x * 256 + threadIdx.x;
    int v = (i < NN) ? indeg[i] : 0;
    if (i < NN) dinv[i] = rsqrtf((float)v + 1.0f);
    sh[threadIdx.x] = v;
    __syncthreads();
    for (int s = 128; s > 0; s >>= 1) {
        if (threadIdx.x < s) sh[threadIdx.x] += sh[threadIdx.x + s];
        __syncthreads();
    }
    if (threadIdx.x == 0) bsum[blockIdx.x] = sh[0];
}

// parallel exclusive scan of the 391 block sums
__global__ void k_scan2(int* __restrict__ bsum, int nb) {
    __shared__ int sh[512];
    int t = threadIdx.x;
    int v = (t < nb) ? bsum[t] : 0;
    sh[t] = v;
    __syncthreads();
    for (int s = 1; s < 512; s <<= 1) {
        int u = (t >= s) ? sh[t - s] : 0;
        __syncthreads();
        sh[t] += u;
        __syncthreads();
    }
    if (t < nb) bsum[t] = sh[t] - v;  // exclusive
}

__global__ void k_scan3(const int* __restrict__ indeg, const int* __restrict__ bsum,
                        int* __restrict__ rowstart) {
    __shared__ int sh[256];
    int i = blockIdx.x * 256 + threadIdx.x;
    int v = (i < NN) ? indeg[i] : 0;
    sh[threadIdx.x] = v;
    __syncthreads();
    for (int s = 1; s < 256; s <<= 1) {
        int t = (threadIdx.x >= s) ? sh[threadIdx.x - s] : 0;
        __syncthreads();
        sh[threadIdx.x] += t;
        __syncthreads();
    }
    if (i < NN) rowstart[i] = bsum[blockIdx.x] + sh[threadIdx.x] - v;  // exclusive
}

// packed CSR entry: .x = src node, .y = coef bits
__global__ void k_fill(const int* __restrict__ src, const int* __restrict__ dst,
                       const int* __restrict__ rowstart, int* __restrict__ cursor,
                       const float* __restrict__ dinv, int2* __restrict__ csr) {
    int e = blockIdx.x * 256 + threadIdx.x;
    if (e < NE) {
        int s = src[e], d = dst[e];
        int p = rowstart[d] + atomicAdd(&cursor[d], 1);
        int2 ent;
        ent.x = s;
        ent.y = __float_as_int(dinv[s] * dinv[d]);
        csr[p] = ent;
    }
}

// ---------------- dense: out[N,64] = in[N,K] @ W[K,64] (+bias,relu optional) ----------------

template<int K, bool BR>
__global__ void k_dense(const float* __restrict__ x, const float* __restrict__ W,
                        const float* __restrict__ bias, float* __restrict__ out) {
    __shared__ float Ws[K * 64];
    __shared__ float xs[4 * K];
    int tid = threadIdx.x;
    for (int i = tid; i < K * 64; i += 256) Ws[i] = W[i];
    int n0 = blockIdx.x * 4;
    for (int i = tid; i < 4 * K; i += 256) xs[i] = x[(size_t)n0 * K + i];
    __syncthreads();
    int nl = tid >> 6, j = tid & 63;
    const float* xr = &xs[nl * K];
    float acc = 0.0f;
#pragma unroll
    for (int k = 0; k < K; k++) acc = fmaf(xr[k], Ws[k * 64 + j], acc);
    if (BR) acc = fmaxf(acc + bias[j], 0.0f);
    out[(size_t)(n0 + nl) * 64 + j] = acc;
}

// ---------------- gather on 64-dim rows: 8-wide MLP, + bias + relu ----------------

__global__ void k_gather8(const float* __restrict__ hlin, const int* __restrict__ rowstart,
                          const int* __restrict__ indeg, const int2* __restrict__ csr,
                          const float* __restrict__ dinv, const float* __restrict__ bias,
                          float* __restrict__ out) {
    int node = blockIdx.x * 4 + (threadIdx.x >> 6);
    int lane = threadIdx.x & 63;
    if (node >= NN) return;
    float di = dinv[node];
    float acc = hlin[(size_t)node * 64 + lane] * (di * di);
    int start = rowstart[node];
    int len   = indeg[node];
    int k = 0;
    for (; k + 8 <= len; k += 8) {
        int2 e0 = csr[start + k + 0];
        int2 e1 = csr[start + k + 1];
        int2 e2 = csr[start + k + 2];
        int2 e3 = csr[start + k + 3];
        int2 e4 = csr[start + k + 4];
        int2 e5 = csr[start + k + 5];
        int2 e6 = csr[start + k + 6];
        int2 e7 = csr[start + k + 7];
        float v0 = hlin[(size_t)e0.x * 64 + lane];
        float v1 = hlin[(size_t)e1.x * 64 + lane];
        float v2 = hlin[(size_t)e2.x * 64 + lane];
        float v3 = hlin[(size_t)e3.x * 64 + lane];
        float v4 = hlin[(size_t)e4.x * 64 + lane];
        float v5 = hlin[(size_t)e5.x * 64 + lane];
        float v6 = hlin[(size_t)e6.x * 64 + lane];
        float v7 = hlin[(size_t)e7.x * 64 + lane];
        acc = fmaf(v0, __int_as_float(e0.y), acc);
        acc = fmaf(v1, __int_as_float(e1.y), acc);
        acc = fmaf(v2, __int_as_float(e2.y), acc);
        acc = fmaf(v3, __int_as_float(e3.y), acc);
        acc = fmaf(v4, __int_as_float(e4.y), acc);
        acc = fmaf(v5, __int_as_float(e5.y), acc);
        acc = fmaf(v6, __int_as_float(e6.y), acc);
        acc = fmaf(v7, __int_as_float(e7.y), acc);
    }
    for (; k + 2 <= len; k += 2) {
        int2 ea = csr[start + k + 0];
        int2 eb = csr[start + k + 1];
        float va = hlin[(size_t)ea.x * 64 + lane];
        float vb = hlin[(size_t)eb.x * 64 + lane];
        acc = fmaf(va, __int_as_float(ea.y), acc);
        acc = fmaf(vb, __int_as_float(eb.y), acc);
    }
    if (k < len) {
        int2 e = csr[start + k];
        acc = fmaf(hlin[(size_t)e.x * 64 + lane], __int_as_float(e.y), acc);
    }
    out[(size_t)node * 64 + lane] = fmaxf(acc + bias[lane], 0.0f);
}

// ---------------- layer-1 gather on RAW x (36-dim rows): gather commutes with W ----------------

__global__ void k_gather36(const float* __restrict__ x, const int* __restrict__ rowstart,
                           const int* __restrict__ indeg, const int2* __restrict__ csr,
                           const float* __restrict__ dinv, float* __restrict__ G) {
    int node = blockIdx.x * 4 + (threadIdx.x >> 6);
    int lane = threadIdx.x & 63;
    if (node >= NN) return;
    bool act = lane < IND;
    float di = dinv[node];
    float acc = act ? x[(size_t)node * IND + lane] * (di * di) : 0.0f;
    int start = rowstart[node];
    int len   = indeg[node];
    int k = 0;
    for (; k + 8 <= len; k += 8) {
        int2 e0 = csr[start + k + 0];
        int2 e1 = csr[start + k + 1];
        int2 e2 = csr[start + k + 2];
        int2 e3 = csr[start + k + 3];
        int2 e4 = csr[start + k + 4];
        int2 e5 = csr[start + k + 5];
        int2 e6 = csr[start + k + 6];
        int2 e7 = csr[start + k + 7];
        float v0 = act ? x[(size_t)e0.x * IND + lane] : 0.0f;
        float v1 = act ? x[(size_t)e1.x * IND + lane] : 0.0f;
        float v2 = act ? x[(size_t)e2.x * IND + lane] : 0.0f;
        float v3 = act ? x[(size_t)e3.x * IND + lane] : 0.0f;
        float v4 = act ? x[(size_t)e4.x * IND + lane] : 0.0f;
        float v5 = act ? x[(size_t)e5.x * IND + lane] : 0.0f;
        float v6 = act ? x[(size_t)e6.x * IND + lane] : 0.0f;
        float v7 = act ? x[(size_t)e7.x * IND + lane] : 0.0f;
        acc = fmaf(v0, __int_as_float(e0.y), acc);
        acc = fmaf(v1, __int_as_float(e1.y), acc);
        acc = fmaf(v2, __int_as_float(e2.y), acc);
        acc = fmaf(v3, __int_as_float(e3.y), acc);
        acc = fmaf(v4, __int_as_float(e4.y), acc);
        acc = fmaf(v5, __int_as_float(e5.y), acc);
        acc = fmaf(v6, __int_as_float(e6.y), acc);
        acc = fmaf(v7, __int_as_float(e7.y), acc);
    }
    for (; k < len; k++) {
        int2 e = csr[start + k];
        float v = act ? x[(size_t)e.x * IND + lane] : 0.0f;
        acc = fmaf(v, __int_as_float(e.y), acc);
    }
    if (act) G[(size_t)node * IND + lane] = acc;
}

// ---------------- pooling (batch is sorted: run-accumulate in registers) ----------------

__global__ void k_pool(const float* __restrict__ h, const int* __restrict__ batch,
                       float* __restrict__ msum, float* __restrict__ mmax,
                       float* __restrict__ cnt) {
    int lane = threadIdx.x & 63;
    int wave = threadIdx.x >> 6;
    int start = blockIdx.x * 256 + wave * 64;
    if (start >= NN) return;
    int end = min(start + 64, NN);
    int cur = batch[start];
    float s = 0.0f, m = 0.0f;
    int run = 0;
    for (int n = start; n < end; n++) {
        int g = batch[n];
        if (g != cur) {
            atomicAdd(&msum[cur * 64 + lane], s);
            atomicMax((int*)&mmax[cur * 64 + lane], __float_as_int(m));
            if (lane == 0) atomicAdd(&cnt[cur], (float)run);
            s = 0.0f; m = 0.0f; run = 0; cur = g;
        }
        float v = h[(size_t)n * 64 + lane];
        s += v;
        m = fmaxf(m, v);
        run++;
    }
    atomicAdd(&msum[cur * 64 + lane], s);
    atomicMax((int*)&mmax[cur * 64 + lane], __float_as_int(m));
    if (lane == 0) atomicAdd(&cnt[cur], (float)run);
}

// ---------------- classifier head ----------------

__global__ void k_cls(const float* __restrict__ msum, const float* __restrict__ mmax,
                      const float* __restrict__ cnt,
                      const float* __restrict__ cw1, const float* __restrict__ cb1,
                      const float* __restrict__ g1,  const float* __restrict__ be1,
                      const float* __restrict__ cw2, const float* __restrict__ cb2,
                      const float* __restrict__ g2,  const float* __restrict__ be2,
                      const float* __restrict__ cw3, const float* __restrict__ cb3,
                      float* __restrict__ out) {
    __shared__ float emb[128];
    __shared__ float z1[64];
    __shared__ float z2[32];
    int g = blockIdx.x;
    int t = threadIdx.x;
    float invc = 1.0f / fmaxf(cnt[g], 1.0f);
    emb[t]      = msum[g * 64 + t] * invc;
    emb[64 + t] = mmax[g * 64 + t];
    __syncthreads();
    float acc = cb1[t];
#pragma unroll
    for (int k = 0; k < 128; k++) acc = fmaf(emb[k], cw1[k * 64 + t], acc);
    acc = acc * (g1[t] / sqrtf(1.0f + BN_EPS)) + be1[t];
    z1[t] = fmaxf(acc, 0.0f);
    __syncthreads();
    if (t < 32) {
        float a = cb2[t];
#pragma unroll
        for (int k = 0; k < 64; k++) a = fmaf(z1[k], cw2[k * 32 + t], a);
        a = a * (g2[t] / sqrtf(1.0f + BN_EPS)) + be2[t];
        z2[t] = fmaxf(a, 0.0f);
    }
    __syncthreads();
    if (t < 5) {
        float a = cb3[t];
#pragma unroll
        for (int k = 0; k < 32; k++) a = fmaf(z2[k], cw3[k * 5 + t], a);
        out[g * 5 + t] = a;
    }
}

// ---------------- launch ----------------

extern "C" void kernel_launch(void* const* d_in, const int* in_sizes, int n_in,
                              void* d_out, int out_size, void* d_ws, size_t ws_size,
                              hipStream_t stream) {
    const float* x     = (const float*)d_in[0];
    const int*   ei    = (const int*)d_in[1];
    const int*   src   = ei;
    const int*   dst   = ei + NE;
    const int*   batch = (const int*)d_in[2];
    const float* W1  = (const float*)d_in[3];
    const float* b1  = (const float*)d_in[4];
    const float* W2  = (const float*)d_in[5];
    const float* b2  = (const float*)d_in[6];
    const float* W3  = (const float*)d_in[7];
    const float* b3  = (const float*)d_in[8];
    const float* cw1 = (const float*)d_in[9];
    const float* cb1 = (const float*)d_in[10];
    const float* g1  = (const float*)d_in[11];
    const float* be1 = (const float*)d_in[12];
    const float* cw2 = (const float*)d_in[13];
    const float* cb2 = (const float*)d_in[14];
    const float* g2  = (const float*)d_in[15];
    const float* be2 = (const float*)d_in[16];
    const float* cw3 = (const float*)d_in[17];
    const float* cb3 = (const float*)d_in[18];
    float* out = (float*)d_out;

    char* ws = (char*)d_ws;
    size_t off = 0;
    auto alloc = [&](size_t bytes) {
        off = (off + 255) & ~(size_t)255;
        void* p = ws + off;
        off += bytes;
        return p;
    };

    int*   indeg    = (int*)alloc(NN * 4);
    float* dinv     = (float*)alloc(NN * 4);
    int*   rowstart = (int*)alloc(NN * 4);
    int*   cursor   = (int*)alloc(NN * 4);
    int*   bsum     = (int*)alloc(512 * 4);
    int2*  csr      = (int2*)alloc((size_t)NE * 8);
    float* A        = (float*)alloc((size_t)NN * 64 * 4);  // also holds G[N,36] for layer 1
    float* B        = (float*)alloc((size_t)NN * 64 * 4);
    float* msum     = (float*)alloc((size_t)NG * 64 * 4);
    float* mmax     = (float*)alloc((size_t)NG * 64 * 4);
    float* cnt      = (float*)alloc((size_t)NG * 4);

    hipMemsetAsync(indeg,  0, NN * 4, stream);
    hipMemsetAsync(cursor, 0, NN * 4, stream);
    hipMemsetAsync(msum,   0, (size_t)NG * 64 * 4, stream);
    hipMemsetAsync(mmax,   0, (size_t)NG * 64 * 4, stream);
    hipMemsetAsync(cnt,    0, (size_t)NG * 4, stream);

    const int NB_E = (NE + 255) / 256;    // 4688
    const int NB_N = (NN + 255) / 256;    // 391

    k_indeg<<<NB_E, 256, 0, stream>>>(dst, indeg);
    k_scan1<<<NB_N, 256, 0, stream>>>(indeg, bsum, dinv);
    k_scan2<<<1, 512, 0, stream>>>(bsum, NB_N);
    k_scan3<<<NB_N, 256, 0, stream>>>(indeg, bsum, rowstart);
    k_fill <<<NB_E, 256, 0, stream>>>(src, dst, rowstart, cursor, dinv, csr);

    const int NB_D = NN / 4;  // 25000

    // layer 1: gather on raw x (36-dim, exact commute), then W1+bias+relu
    k_gather36<<<NB_D, 256, 0, stream>>>(x, rowstart, indeg, csr, dinv, A);
    k_dense<IND, true><<<NB_D, 256, 0, stream>>>(A, W1, b1, B);
    // layer 2
    k_dense<HIDD, false><<<NB_D, 256, 0, stream>>>(B, W2, nullptr, A);
    k_gather8<<<NB_D, 256, 0, stream>>>(A, rowstart, indeg, csr, dinv, b2, B);
    // layer 3
    k_dense<HIDD, false><<<NB_D, 256, 0, stream>>>(B, W3, nullptr, A);
    k_gather8<<<NB_D, 256, 0, stream>>>(A, rowstart, indeg, csr, dinv, b3, B);

    k_pool<<<NB_N, 256, 0, stream>>>(B, batch, msum, mmax, cnt);

    k_cls<<<NG, 64, 0, stream>>>(msum, mmax, cnt, cw1, cb1, g1, be1,
                                 cw2, cb2, g2, be2, cw3, cb3, out);
}

// Round 7
// 450.010 us; speedup vs baseline: 1.0854x; 1.0854x over previous
//
#include <hip/hip_runtime.h>

#define NN 100000
#define NE 1200000
#define NG 2000
#define IND 36
#define HIDD 64
#define BN_EPS 1e-5f

// ---------------- init: zero all accumulator buffers in one launch ----------------

__global__ void k_init(int* __restrict__ indeg, float* __restrict__ msum,
                       float* __restrict__ mmax, float* __restrict__ cnt) {
    int i = blockIdx.x * 256 + threadIdx.x;
    int stride = gridDim.x * 256;
    for (int j = i; j < NN; j += stride) indeg[j] = 0;
    for (int j = i; j < NG * 64; j += stride) { msum[j] = 0.0f; mmax[j] = 0.0f; }
    for (int j = i; j < NG; j += stride) cnt[j] = 0.0f;
}

// ---------------- CSR build ----------------

// indegree histogram; atomic return value = slot of this edge within its dst row
__global__ void k_indeg(const int* __restrict__ dst, int* __restrict__ indeg,
                        int* __restrict__ slot) {
    int e = blockIdx.x * 256 + threadIdx.x;
    if (e < NE) slot[e] = atomicAdd(&indeg[dst[e]], 1);
}

// block-sum for scan + dinv (folded in: reads indeg anyway)
__global__ void k_scan1(const int* __restrict__ indeg, int* __restrict__ bsum,
                        float* __restrict__ dinv) {
    __shared__ int sh[256];
    int i = blockIdx.x * 256 + threadIdx.x;
    int v = (i < NN) ? indeg[i] : 0;
    if (i < NN) dinv[i] = rsqrtf((float)v + 1.0f);
    sh[threadIdx.x] = v;
    __syncthreads();
    for (int s = 128; s > 0; s >>= 1) {
        if (threadIdx.x < s) sh[threadIdx.x] += sh[threadIdx.x + s];
        __syncthreads();
    }
    if (threadIdx.x == 0) bsum[blockIdx.x] = sh[0];
}

// parallel exclusive scan of the 391 block sums
__global__ void k_scan2(int* __restrict__ bsum, int nb) {
    __shared__ int sh[512];
    int t = threadIdx.x;
    int v = (t < nb) ? bsum[t] : 0;
    sh[t] = v;
    __syncthreads();
    for (int s = 1; s < 512; s <<= 1) {
        int u = (t >= s) ? sh[t - s] : 0;
        __syncthreads();
        sh[t] += u;
        __syncthreads();
    }
    if (t < nb) bsum[t] = sh[t] - v;  // exclusive
}

__global__ void k_scan3(const int* __restrict__ indeg, const int* __restrict__ bsum,
                        int* __restrict__ rowstart) {
    __shared__ int sh[256];
    int i = blockIdx.x * 256 + threadIdx.x;
    int v = (i < NN) ? indeg[i] : 0;
    sh[threadIdx.x] = v;
    __syncthreads();
    for (int s = 1; s < 256; s <<= 1) {
        int t = (threadIdx.x >= s) ? sh[threadIdx.x - s] : 0;
        __syncthreads();
        sh[threadIdx.x] += t;
        __syncthreads();
    }
    if (i < NN) rowstart[i] = bsum[blockIdx.x] + sh[threadIdx.x] - v;  // exclusive
}

// packed CSR entry: .x = src node, .y = coef bits. No atomics (slot precomputed).
__global__ void k_fill(const int* __restrict__ src, const int* __restrict__ dst,
                       const int* __restrict__ rowstart, const int* __restrict__ slot,
                       const float* __restrict__ dinv, int2* __restrict__ csr) {
    int e = blockIdx.x * 256 + threadIdx.x;
    if (e < NE) {
        int s = src[e], d = dst[e];
        int p = rowstart[d] + slot[e];
        int2 ent;
        ent.x = s;
        ent.y = __float_as_int(dinv[s] * dinv[d]);
        csr[p] = ent;
    }
}

// ---------------- dense: out[N,64] = in[N,K] @ W[K,64] ----------------

template<int K>
__global__ void k_dense(const float* __restrict__ x, const float* __restrict__ W,
                        float* __restrict__ out) {
    __shared__ float Ws[K * 64];
    __shared__ float xs[4 * K];
    int tid = threadIdx.x;
    for (int i = tid; i < K * 64; i += 256) Ws[i] = W[i];
    int n0 = blockIdx.x * 4;
    for (int i = tid; i < 4 * K; i += 256) xs[i] = x[(size_t)n0 * K + i];
    __syncthreads();
    int nl = tid >> 6, j = tid & 63;
    const float* xr = &xs[nl * K];
    float acc = 0.0f;
#pragma unroll
    for (int k = 0; k < K; k++) acc = fmaf(xr[k], Ws[k * 64 + j], acc);
    out[(size_t)(n0 + nl) * 64 + j] = acc;
}

// ---------------- gather: 16-deep MLP inner loop, + bias + relu ----------------

__global__ void k_gather16(const float* __restrict__ hlin, const int* __restrict__ rowstart,
                           const int* __restrict__ indeg, const int2* __restrict__ csr,
                           const float* __restrict__ dinv, const float* __restrict__ bias,
                           float* __restrict__ out) {
    int node = blockIdx.x * 4 + (threadIdx.x >> 6);
    int lane = threadIdx.x & 63;
    if (node >= NN) return;
    float di = dinv[node];
    float acc = hlin[(size_t)node * 64 + lane] * (di * di);
    int start = rowstart[node];
    int len   = indeg[node];
    int k = 0;
    for (; k + 16 <= len; k += 16) {
        int2 e[16];
        float v[16];
#pragma unroll
        for (int u = 0; u < 16; u++) e[u] = csr[start + k + u];
#pragma unroll
        for (int u = 0; u < 16; u++) v[u] = hlin[(size_t)e[u].x * 64 + lane];
#pragma unroll
        for (int u = 0; u < 16; u++) acc = fmaf(v[u], __int_as_float(e[u].y), acc);
    }
    for (; k + 4 <= len; k += 4) {
        int2 e[4];
        float v[4];
#pragma unroll
        for (int u = 0; u < 4; u++) e[u] = csr[start + k + u];
#pragma unroll
        for (int u = 0; u < 4; u++) v[u] = hlin[(size_t)e[u].x * 64 + lane];
#pragma unroll
        for (int u = 0; u < 4; u++) acc = fmaf(v[u], __int_as_float(e[u].y), acc);
    }
    for (; k < len; k++) {
        int2 e = csr[start + k];
        acc = fmaf(hlin[(size_t)e.x * 64 + lane], __int_as_float(e.y), acc);
    }
    out[(size_t)node * 64 + lane] = fmaxf(acc + bias[lane], 0.0f);
}

// ---------------- pooling (batch is sorted: run-accumulate in registers) ----------------

__global__ void k_pool(const float* __restrict__ h, const int* __restrict__ batch,
                       float* __restrict__ msum, float* __restrict__ mmax,
                       float* __restrict__ cnt) {
    int lane = threadIdx.x & 63;
    int wave = threadIdx.x >> 6;
    int start = blockIdx.x * 256 + wave * 64;
    if (start >= NN) return;
    int end = min(start + 64, NN);
    int cur = batch[start];
    float s = 0.0f, m = 0.0f;
    int run = 0;
    for (int n = start; n < end; n++) {
        int g = batch[n];
        if (g != cur) {
            atomicAdd(&msum[cur * 64 + lane], s);
            atomicMax((int*)&mmax[cur * 64 + lane], __float_as_int(m));
            if (lane == 0) atomicAdd(&cnt[cur], (float)run);
            s = 0.0f; m = 0.0f; run = 0; cur = g;
        }
        float v = h[(size_t)n * 64 + lane];
        s += v;
        m = fmaxf(m, v);
        run++;
    }
    atomicAdd(&msum[cur * 64 + lane], s);
    atomicMax((int*)&mmax[cur * 64 + lane], __float_as_int(m));
    if (lane == 0) atomicAdd(&cnt[cur], (float)run);
}

// ---------------- classifier head ----------------

__global__ void k_cls(const float* __restrict__ msum, const float* __restrict__ mmax,
                      const float* __restrict__ cnt,
                      const float* __restrict__ cw1, const float* __restrict__ cb1,
                      const float* __restrict__ g1,  const float* __restrict__ be1,
                      const float* __restrict__ cw2, const float* __restrict__ cb2,
                      const float* __restrict__ g2,  const float* __restrict__ be2,
                      const float* __restrict__ cw3, const float* __restrict__ cb3,
                      float* __restrict__ out) {
    __shared__ float emb[128];
    __shared__ float z1[64];
    __shared__ float z2[32];
    int g = blockIdx.x;
    int t = threadIdx.x;
    float invc = 1.0f / fmaxf(cnt[g], 1.0f);
    emb[t]      = msum[g * 64 + t] * invc;
    emb[64 + t] = mmax[g * 64 + t];
    __syncthreads();
    float acc = cb1[t];
#pragma unroll
    for (int k = 0; k < 128; k++) acc = fmaf(emb[k], cw1[k * 64 + t], acc);
    acc = acc * (g1[t] / sqrtf(1.0f + BN_EPS)) + be1[t];
    z1[t] = fmaxf(acc, 0.0f);
    __syncthreads();
    if (t < 32) {
        float a = cb2[t];
#pragma unroll
        for (int k = 0; k < 64; k++) a = fmaf(z1[k], cw2[k * 32 + t], a);
        a = a * (g2[t] / sqrtf(1.0f + BN_EPS)) + be2[t];
        z2[t] = fmaxf(a, 0.0f);
    }
    __syncthreads();
    if (t < 5) {
        float a = cb3[t];
#pragma unroll
        for (int k = 0; k < 32; k++) a = fmaf(z2[k], cw3[k * 5 + t], a);
        out[g * 5 + t] = a;
    }
}

// ---------------- launch ----------------

extern "C" void kernel_launch(void* const* d_in, const int* in_sizes, int n_in,
                              void* d_out, int out_size, void* d_ws, size_t ws_size,
                              hipStream_t stream) {
    const float* x     = (const float*)d_in[0];
    const int*   ei    = (const int*)d_in[1];
    const int*   src   = ei;
    const int*   dst   = ei + NE;
    const int*   batch = (const int*)d_in[2];
    const float* W1  = (const float*)d_in[3];
    const float* b1  = (const float*)d_in[4];
    const float* W2  = (const float*)d_in[5];
    const float* b2  = (const float*)d_in[6];
    const float* W3  = (const float*)d_in[7];
    const float* b3  = (const float*)d_in[8];
    const float* cw1 = (const float*)d_in[9];
    const float* cb1 = (const float*)d_in[10];
    const float* g1  = (const float*)d_in[11];
    const float* be1 = (const float*)d_in[12];
    const float* cw2 = (const float*)d_in[13];
    const float* cb2 = (const float*)d_in[14];
    const float* g2  = (const float*)d_in[15];
    const float* be2 = (const float*)d_in[16];
    const float* cw3 = (const float*)d_in[17];
    const float* cb3 = (const float*)d_in[18];
    float* out = (float*)d_out;

    char* ws = (char*)d_ws;
    size_t off = 0;
    auto alloc = [&](size_t bytes) {
        off = (off + 255) & ~(size_t)255;
        void* p = ws + off;
        off += bytes;
        return p;
    };

    int*   indeg    = (int*)alloc(NN * 4);
    float* dinv     = (float*)alloc(NN * 4);
    int*   rowstart = (int*)alloc(NN * 4);
    int*   slot     = (int*)alloc((size_t)NE * 4);
    int*   bsum     = (int*)alloc(512 * 4);
    int2*  csr      = (int2*)alloc((size_t)NE * 8);
    float* A        = (float*)alloc((size_t)NN * 64 * 4);
    float* B        = (float*)alloc((size_t)NN * 64 * 4);
    float* msum     = (float*)alloc((size_t)NG * 64 * 4);
    float* mmax     = (float*)alloc((size_t)NG * 64 * 4);
    float* cnt      = (float*)alloc((size_t)NG * 4);

    const int NB_E = (NE + 255) / 256;    // 4688
    const int NB_N = (NN + 255) / 256;    // 391

    k_init <<<256, 256, 0, stream>>>(indeg, msum, mmax, cnt);
    k_indeg<<<NB_E, 256, 0, stream>>>(dst, indeg, slot);
    k_scan1<<<NB_N, 256, 0, stream>>>(indeg, bsum, dinv);
    k_scan2<<<1, 512, 0, stream>>>(bsum, NB_N);
    k_scan3<<<NB_N, 256, 0, stream>>>(indeg, bsum, rowstart);
    k_fill <<<NB_E, 256, 0, stream>>>(src, dst, rowstart, slot, dinv, csr);

    const int NB_D = NN / 4;  // 25000

    // layer 1
    k_dense<IND><<<NB_D, 256, 0, stream>>>(x, W1, A);
    k_gather16<<<NB_D, 256, 0, stream>>>(A, rowstart, indeg, csr, dinv, b1, B);
    // layer 2
    k_dense<HIDD><<<NB_D, 256, 0, stream>>>(B, W2, A);
    k_gather16<<<NB_D, 256, 0, stream>>>(A, rowstart, indeg, csr, dinv, b2, B);
    // layer 3
    k_dense<HIDD><<<NB_D, 256, 0, stream>>>(B, W3, A);
    k_gather16<<<NB_D, 256, 0, stream>>>(A, rowstart, indeg, csr, dinv, b3, B);

    k_pool<<<NB_N, 256, 0, stream>>>(B, batch, msum, mmax, cnt);

    k_cls<<<NG, 64, 0, stream>>>(msum, mmax, cnt, cw1, cb1, g1, be1,
                                 cw2, cb2, g2, be2, cw3, cb3, out);
}

// Round 8
// 438.984 us; speedup vs baseline: 1.1127x; 1.0251x over previous
//
#include <hip/hip_runtime.h>
#include <hip/hip_fp16.h>

#define NN 100000
#define NE 1200000
#define NG 2000
#define IND 36
#define HIDD 64
#define BN_EPS 1e-5f

__device__ __forceinline__ float toF(float v) { return v; }
__device__ __forceinline__ float toF(__half v) { return __half2float(v); }

// ---------------- init: zero all accumulator buffers in one launch ----------------

__global__ void k_init(int* __restrict__ indeg, float* __restrict__ msum,
                       float* __restrict__ mmax, float* __restrict__ cnt) {
    int i = blockIdx.x * 256 + threadIdx.x;
    int stride = gridDim.x * 256;
    for (int j = i; j < NN; j += stride) indeg[j] = 0;
    for (int j = i; j < NG * 64; j += stride) { msum[j] = 0.0f; mmax[j] = 0.0f; }
    for (int j = i; j < NG; j += stride) cnt[j] = 0.0f;
}

// ---------------- CSR build ----------------

// indegree histogram; atomic return value = slot of this edge within its dst row
__global__ void k_indeg(const int* __restrict__ dst, int* __restrict__ indeg,
                        int* __restrict__ slot) {
    int e = blockIdx.x * 256 + threadIdx.x;
    if (e < NE) slot[e] = atomicAdd(&indeg[dst[e]], 1);
}

// block-sum for scan + dinv (folded in: reads indeg anyway)
__global__ void k_scan1(const int* __restrict__ indeg, int* __restrict__ bsum,
                        float* __restrict__ dinv) {
    __shared__ int sh[256];
    int i = blockIdx.x * 256 + threadIdx.x;
    int v = (i < NN) ? indeg[i] : 0;
    if (i < NN) dinv[i] = rsqrtf((float)v + 1.0f);
    sh[threadIdx.x] = v;
    __syncthreads();
    for (int s = 128; s > 0; s >>= 1) {
        if (threadIdx.x < s) sh[threadIdx.x] += sh[threadIdx.x + s];
        __syncthreads();
    }
    if (threadIdx.x == 0) bsum[blockIdx.x] = sh[0];
}

// parallel exclusive scan of the 391 block sums
__global__ void k_scan2(int* __restrict__ bsum, int nb) {
    __shared__ int sh[512];
    int t = threadIdx.x;
    int v = (t < nb) ? bsum[t] : 0;
    sh[t] = v;
    __syncthreads();
    for (int s = 1; s < 512; s <<= 1) {
        int u = (t >= s) ? sh[t - s] : 0;
        __syncthreads();
        sh[t] += u;
        __syncthreads();
    }
    if (t < nb) bsum[t] = sh[t] - v;  // exclusive
}

__global__ void k_scan3(const int* __restrict__ indeg, const int* __restrict__ bsum,
                        int* __restrict__ rowstart) {
    __shared__ int sh[256];
    int i = blockIdx.x * 256 + threadIdx.x;
    int v = (i < NN) ? indeg[i] : 0;
    sh[threadIdx.x] = v;
    __syncthreads();
    for (int s = 1; s < 256; s <<= 1) {
        int t = (threadIdx.x >= s) ? sh[threadIdx.x - s] : 0;
        __syncthreads();
        sh[threadIdx.x] += t;
        __syncthreads();
    }
    if (i < NN) rowstart[i] = bsum[blockIdx.x] + sh[threadIdx.x] - v;  // exclusive
}

// packed CSR entry: .x = src node, .y = coef bits. No atomics (slot precomputed).
__global__ void k_fill(const int* __restrict__ src, const int* __restrict__ dst,
                       const int* __restrict__ rowstart, const int* __restrict__ slot,
                       const float* __restrict__ dinv, int2* __restrict__ csr) {
    int e = blockIdx.x * 256 + threadIdx.x;
    if (e < NE) {
        int s = src[e], d = dst[e];
        int p = rowstart[d] + slot[e];
        int2 ent;
        ent.x = s;
        ent.y = __float_as_int(dinv[s] * dinv[d]);
        csr[p] = ent;
    }
}

// ---------------- dense: out[N,64] = in[N,K] @ W[K,64], fp16 out ----------------

template<int K, typename TIN>
__global__ void k_dense(const TIN* __restrict__ x, const float* __restrict__ W,
                        __half* __restrict__ out) {
    __shared__ float Ws[K * 64];
    __shared__ float xs[4 * K];
    int tid = threadIdx.x;
    for (int i = tid; i < K * 64; i += 256) Ws[i] = W[i];
    int n0 = blockIdx.x * 4;
    for (int i = tid; i < 4 * K; i += 256) xs[i] = toF(x[(size_t)n0 * K + i]);
    __syncthreads();
    int nl = tid >> 6, j = tid & 63;
    const float* xr = &xs[nl * K];
    float acc = 0.0f;
#pragma unroll
    for (int k = 0; k < K; k++) acc = fmaf(xr[k], Ws[k * 64 + j], acc);
    out[(size_t)(n0 + nl) * 64 + j] = __float2half(acc);
}

// ---------------- gather: 16-deep MLP on fp16 rows, f32 accumulate, + bias + relu ----------------

__global__ void k_gather16(const __half* __restrict__ hlin, const int* __restrict__ rowstart,
                           const int* __restrict__ indeg, const int2* __restrict__ csr,
                           const float* __restrict__ dinv, const float* __restrict__ bias,
                           __half* __restrict__ out) {
    int node = blockIdx.x * 4 + (threadIdx.x >> 6);
    int lane = threadIdx.x & 63;
    if (node >= NN) return;
    float di = dinv[node];
    float acc = __half2float(hlin[(size_t)node * 64 + lane]) * (di * di);
    int start = rowstart[node];
    int len   = indeg[node];
    int k = 0;
    for (; k + 16 <= len; k += 16) {
        int2 e[16];
        float v[16];
#pragma unroll
        for (int u = 0; u < 16; u++) e[u] = csr[start + k + u];
#pragma unroll
        for (int u = 0; u < 16; u++) v[u] = __half2float(hlin[(size_t)e[u].x * 64 + lane]);
#pragma unroll
        for (int u = 0; u < 16; u++) acc = fmaf(v[u], __int_as_float(e[u].y), acc);
    }
    for (; k + 4 <= len; k += 4) {
        int2 e[4];
        float v[4];
#pragma unroll
        for (int u = 0; u < 4; u++) e[u] = csr[start + k + u];
#pragma unroll
        for (int u = 0; u < 4; u++) v[u] = __half2float(hlin[(size_t)e[u].x * 64 + lane]);
#pragma unroll
        for (int u = 0; u < 4; u++) acc = fmaf(v[u], __int_as_float(e[u].y), acc);
    }
    for (; k < len; k++) {
        int2 e = csr[start + k];
        acc = fmaf(__half2float(hlin[(size_t)e.x * 64 + lane]), __int_as_float(e.y), acc);
    }
    out[(size_t)node * 64 + lane] = __float2half(fmaxf(acc + bias[lane], 0.0f));
}

// ---------------- pooling (batch is sorted: run-accumulate in registers) ----------------

__global__ void k_pool(const __half* __restrict__ h, const int* __restrict__ batch,
                       float* __restrict__ msum, float* __restrict__ mmax,
                       float* __restrict__ cnt) {
    int lane = threadIdx.x & 63;
    int wave = threadIdx.x >> 6;
    int start = blockIdx.x * 256 + wave * 64;
    if (start >= NN) return;
    int end = min(start + 64, NN);
    int cur = batch[start];
    float s = 0.0f, m = 0.0f;
    int run = 0;
    for (int n = start; n < end; n++) {
        int g = batch[n];
        if (g != cur) {
            atomicAdd(&msum[cur * 64 + lane], s);
            atomicMax((int*)&mmax[cur * 64 + lane], __float_as_int(m));
            if (lane == 0) atomicAdd(&cnt[cur], (float)run);
            s = 0.0f; m = 0.0f; run = 0; cur = g;
        }
        float v = __half2float(h[(size_t)n * 64 + lane]);
        s += v;
        m = fmaxf(m, v);
        run++;
    }
    atomicAdd(&msum[cur * 64 + lane], s);
    atomicMax((int*)&mmax[cur * 64 + lane], __float_as_int(m));
    if (lane == 0) atomicAdd(&cnt[cur], (float)run);
}

// ---------------- classifier head ----------------

__global__ void k_cls(const float* __restrict__ msum, const float* __restrict__ mmax,
                      const float* __restrict__ cnt,
                      const float* __restrict__ cw1, const float* __restrict__ cb1,
                      const float* __restrict__ g1,  const float* __restrict__ be1,
                      const float* __restrict__ cw2, const float* __restrict__ cb2,
                      const float* __restrict__ g2,  const float* __restrict__ be2,
                      const float* __restrict__ cw3, const float* __restrict__ cb3,
                      float* __restrict__ out) {
    __shared__ float emb[128];
    __shared__ float z1[64];
    __shared__ float z2[32];
    int g = blockIdx.x;
    int t = threadIdx.x;
    float invc = 1.0f / fmaxf(cnt[g], 1.0f);
    emb[t]      = msum[g * 64 + t] * invc;
    emb[64 + t] = mmax[g * 64 + t];
    __syncthreads();
    float acc = cb1[t];
#pragma unroll
    for (int k = 0; k < 128; k++) acc = fmaf(emb[k], cw1[k * 64 + t], acc);
    acc = acc * (g1[t] / sqrtf(1.0f + BN_EPS)) + be1[t];
    z1[t] = fmaxf(acc, 0.0f);
    __syncthreads();
    if (t < 32) {
        float a = cb2[t];
#pragma unroll
        for (int k = 0; k < 64; k++) a = fmaf(z1[k], cw2[k * 32 + t], a);
        a = a * (g2[t] / sqrtf(1.0f + BN_EPS)) + be2[t];
        z2[t] = fmaxf(a, 0.0f);
    }
    __syncthreads();
    if (t < 5) {
        float a = cb3[t];
#pragma unroll
        for (int k = 0; k < 32; k++) a = fmaf(z2[k], cw3[k * 5 + t], a);
        out[g * 5 + t] = a;
    }
}

// ---------------- launch ----------------

extern "C" void kernel_launch(void* const* d_in, const int* in_sizes, int n_in,
                              void* d_out, int out_size, void* d_ws, size_t ws_size,
                              hipStream_t stream) {
    const float* x     = (const float*)d_in[0];
    const int*   ei    = (const int*)d_in[1];
    const int*   src   = ei;
    const int*   dst   = ei + NE;
    const int*   batch = (const int*)d_in[2];
    const float* W1  = (const float*)d_in[3];
    const float* b1  = (const float*)d_in[4];
    const float* W2  = (const float*)d_in[5];
    const float* b2  = (const float*)d_in[6];
    const float* W3  = (const float*)d_in[7];
    const float* b3  = (const float*)d_in[8];
    const float* cw1 = (const float*)d_in[9];
    const float* cb1 = (const float*)d_in[10];
    const float* g1  = (const float*)d_in[11];
    const float* be1 = (const float*)d_in[12];
    const float* cw2 = (const float*)d_in[13];
    const float* cb2 = (const float*)d_in[14];
    const float* g2  = (const float*)d_in[15];
    const float* be2 = (const float*)d_in[16];
    const float* cw3 = (const float*)d_in[17];
    const float* cb3 = (const float*)d_in[18];
    float* out = (float*)d_out;

    char* ws = (char*)d_ws;
    size_t off = 0;
    auto alloc = [&](size_t bytes) {
        off = (off + 255) & ~(size_t)255;
        void* p = ws + off;
        off += bytes;
        return p;
    };

    int*    indeg    = (int*)alloc(NN * 4);
    float*  dinv     = (float*)alloc(NN * 4);
    int*    rowstart = (int*)alloc(NN * 4);
    int*    slot     = (int*)alloc((size_t)NE * 4);
    int*    bsum     = (int*)alloc(512 * 4);
    int2*   csr      = (int2*)alloc((size_t)NE * 8);
    __half* A        = (__half*)alloc((size_t)NN * 64 * 2);
    __half* B        = (__half*)alloc((size_t)NN * 64 * 2);
    float*  msum     = (float*)alloc((size_t)NG * 64 * 4);
    float*  mmax     = (float*)alloc((size_t)NG * 64 * 4);
    float*  cnt      = (float*)alloc((size_t)NG * 4);

    const int NB_E = (NE + 255) / 256;    // 4688
    const int NB_N = (NN + 255) / 256;    // 391

    k_init <<<256, 256, 0, stream>>>(indeg, msum, mmax, cnt);
    k_indeg<<<NB_E, 256, 0, stream>>>(dst, indeg, slot);
    k_scan1<<<NB_N, 256, 0, stream>>>(indeg, bsum, dinv);
    k_scan2<<<1, 512, 0, stream>>>(bsum, NB_N);
    k_scan3<<<NB_N, 256, 0, stream>>>(indeg, bsum, rowstart);
    k_fill <<<NB_E, 256, 0, stream>>>(src, dst, rowstart, slot, dinv, csr);

    const int NB_D = NN / 4;  // 25000

    // layer 1
    k_dense<IND, float><<<NB_D, 256, 0, stream>>>(x, W1, A);
    k_gather16<<<NB_D, 256, 0, stream>>>(A, rowstart, indeg, csr, dinv, b1, B);
    // layer 2
    k_dense<HIDD, __half><<<NB_D, 256, 0, stream>>>(B, W2, A);
    k_gather16<<<NB_D, 256, 0, stream>>>(A, rowstart, indeg, csr, dinv, b2, B);
    // layer 3
    k_dense<HIDD, __half><<<NB_D, 256, 0, stream>>>(B, W3, A);
    k_gather16<<<NB_D, 256, 0, stream>>>(A, rowstart, indeg, csr, dinv, b3, B);

    k_pool<<<NB_N, 256, 0, stream>>>(B, batch, msum, mmax, cnt);

    k_cls<<<NG, 64, 0, stream>>>(msum, mmax, cnt, cw1, cb1, g1, be1,
                                 cw2, cb2, g2, be2, cw3, cb3, out);
}

// Round 9
// 413.731 us; speedup vs baseline: 1.1806x; 1.0610x over previous
//
#include <hip/hip_runtime.h>
#include <hip/hip_fp16.h>

#define NN 100000
#define NE 1200000
#define NG 2000
#define IND 36
#define HIDD 64
#define BN_EPS 1e-5f

__device__ __forceinline__ float toF(float v) { return v; }
__device__ __forceinline__ float toF(__half v) { return __half2float(v); }

// fma of 4 packed halves (one 8B register pair) into 4 f32 accumulators
__device__ __forceinline__ void fma4u(float& a0, float& a1, float& a2, float& a3,
                                      uint2 raw, float c) {
    __half2 u, v;
    *reinterpret_cast<unsigned*>(&u) = raw.x;
    *reinterpret_cast<unsigned*>(&v) = raw.y;
    float2 uf = __half22float2(u);
    float2 vf = __half22float2(v);
    a0 = fmaf(uf.x, c, a0);
    a1 = fmaf(uf.y, c, a1);
    a2 = fmaf(vf.x, c, a2);
    a3 = fmaf(vf.y, c, a3);
}

// ---------------- init: zero all accumulator buffers in one launch ----------------

__global__ void k_init(int* __restrict__ indeg, float* __restrict__ msum,
                       float* __restrict__ mmax, float* __restrict__ cnt) {
    int i = blockIdx.x * 256 + threadIdx.x;
    int stride = gridDim.x * 256;
    for (int j = i; j < NN; j += stride) indeg[j] = 0;
    for (int j = i; j < NG * 64; j += stride) { msum[j] = 0.0f; mmax[j] = 0.0f; }
    for (int j = i; j < NG; j += stride) cnt[j] = 0.0f;
}

// ---------------- CSR build ----------------

__global__ void k_indeg(const int* __restrict__ dst, int* __restrict__ indeg,
                        int* __restrict__ slot) {
    int e = blockIdx.x * 256 + threadIdx.x;
    if (e < NE) slot[e] = atomicAdd(&indeg[dst[e]], 1);
}

__global__ void k_scan1(const int* __restrict__ indeg, int* __restrict__ bsum,
                        float* __restrict__ dinv) {
    __shared__ int sh[256];
    int i = blockIdx.x * 256 + threadIdx.x;
    int v = (i < NN) ? indeg[i] : 0;
    if (i < NN) dinv[i] = rsqrtf((float)v + 1.0f);
    sh[threadIdx.x] = v;
    __syncthreads();
    for (int s = 128; s > 0; s >>= 1) {
        if (threadIdx.x < s) sh[threadIdx.x] += sh[threadIdx.x + s];
        __syncthreads();
    }
    if (threadIdx.x == 0) bsum[blockIdx.x] = sh[0];
}

__global__ void k_scan2(int* __restrict__ bsum, int nb) {
    __shared__ int sh[512];
    int t = threadIdx.x;
    int v = (t < nb) ? bsum[t] : 0;
    sh[t] = v;
    __syncthreads();
    for (int s = 1; s < 512; s <<= 1) {
        int u = (t >= s) ? sh[t - s] : 0;
        __syncthreads();
        sh[t] += u;
        __syncthreads();
    }
    if (t < nb) bsum[t] = sh[t] - v;  // exclusive
}

__global__ void k_scan3(const int* __restrict__ indeg, const int* __restrict__ bsum,
                        int* __restrict__ rowstart) {
    __shared__ int sh[256];
    int i = blockIdx.x * 256 + threadIdx.x;
    int v = (i < NN) ? indeg[i] : 0;
    sh[threadIdx.x] = v;
    __syncthreads();
    for (int s = 1; s < 256; s <<= 1) {
        int t = (threadIdx.x >= s) ? sh[threadIdx.x - s] : 0;
        __syncthreads();
        sh[threadIdx.x] += t;
        __syncthreads();
    }
    if (i < NN) rowstart[i] = bsum[blockIdx.x] + sh[threadIdx.x] - v;  // exclusive
}

__global__ void k_fill(const int* __restrict__ src, const int* __restrict__ dst,
                       const int* __restrict__ rowstart, const int* __restrict__ slot,
                       const float* __restrict__ dinv, int2* __restrict__ csr) {
    int e = blockIdx.x * 256 + threadIdx.x;
    if (e < NE) {
        int s = src[e], d = dst[e];
        int p = rowstart[d] + slot[e];
        int2 ent;
        ent.x = s;
        ent.y = __float_as_int(dinv[s] * dinv[d]);
        csr[p] = ent;
    }
}

// ---------------- dense: out[N,64] = in[N,K] @ W[K,64], fp16 out ----------------

template<int K, typename TIN>
__global__ void k_dense(const TIN* __restrict__ x, const float* __restrict__ W,
                        __half* __restrict__ out) {
    __shared__ float Ws[K * 64];
    __shared__ float xs[4 * K];
    int tid = threadIdx.x;
    for (int i = tid; i < K * 64; i += 256) Ws[i] = W[i];
    int n0 = blockIdx.x * 4;
    for (int i = tid; i < 4 * K; i += 256) xs[i] = toF(x[(size_t)n0 * K + i]);
    __syncthreads();
    int nl = tid >> 6, j = tid & 63;
    const float* xr = &xs[nl * K];
    float acc = 0.0f;
#pragma unroll
    for (int k = 0; k < K; k++) acc = fmaf(xr[k], Ws[k * 64 + j], acc);
    out[(size_t)(n0 + nl) * 64 + j] = __float2half(acc);
}

// ---------------- gather: 4 edges per load instruction ----------------
// Wave layout: sub = lane>>4 (edge slot 0..3), fl = lane&15 (feature quad).
// Each 16-lane group loads one edge row as half4 (8B/lane); 4 random rows per instr.
// Epilogue: shfl_xor(16) + shfl_xor(32) sums the 4 edge-partials.

__global__ void k_gather4e(const __half* __restrict__ hlin, const int* __restrict__ rowstart,
                           const int* __restrict__ indeg, const int2* __restrict__ csr,
                           const float* __restrict__ dinv, const float* __restrict__ bias,
                           __half* __restrict__ out) {
    int node = blockIdx.x * 4 + (threadIdx.x >> 6);
    int lane = threadIdx.x & 63;
    int sub  = (lane >> 4);
    int fl   = lane & 15;
    if (node >= NN) return;

    float di = dinv[node];
    float a0 = 0, a1 = 0, a2 = 0, a3 = 0;
    {   // self loop, counted only in sub==0
        uint2 sv = *reinterpret_cast<const uint2*>(hlin + (size_t)node * 64 + 4 * fl);
        float m = (sub == 0) ? di * di : 0.0f;
        fma4u(a0, a1, a2, a3, sv, m);
    }

    int start = rowstart[node];
    int len   = indeg[node];
    for (int k = 0; k < len; k += 8) {
        int i0 = k + sub;
        int i1 = k + 4 + sub;
        int2 e0 = (i0 < len) ? csr[start + i0] : make_int2(0, 0);
        int2 e1 = (i1 < len) ? csr[start + i1] : make_int2(0, 0);
        uint2 r0 = *reinterpret_cast<const uint2*>(hlin + (size_t)e0.x * 64 + 4 * fl);
        uint2 r1 = *reinterpret_cast<const uint2*>(hlin + (size_t)e1.x * 64 + 4 * fl);
        fma4u(a0, a1, a2, a3, r0, __int_as_float(e0.y));
        fma4u(a0, a1, a2, a3, r1, __int_as_float(e1.y));
    }

    // sum the 4 edge-slot partials across sub groups
    a0 += __shfl_xor(a0, 16, 64);  a1 += __shfl_xor(a1, 16, 64);
    a2 += __shfl_xor(a2, 16, 64);  a3 += __shfl_xor(a3, 16, 64);
    a0 += __shfl_xor(a0, 32, 64);  a1 += __shfl_xor(a1, 32, 64);
    a2 += __shfl_xor(a2, 32, 64);  a3 += __shfl_xor(a3, 32, 64);

    if (sub == 0) {
        float4 b = *reinterpret_cast<const float4*>(bias + 4 * fl);
        float o0 = fmaxf(a0 + b.x, 0.0f);
        float o1 = fmaxf(a1 + b.y, 0.0f);
        float o2 = fmaxf(a2 + b.z, 0.0f);
        float o3 = fmaxf(a3 + b.w, 0.0f);
        __half2 p01 = __floats2half2_rn(o0, o1);
        __half2 p23 = __floats2half2_rn(o2, o3);
        uint2 pk;
        pk.x = *reinterpret_cast<unsigned*>(&p01);
        pk.y = *reinterpret_cast<unsigned*>(&p23);
        *reinterpret_cast<uint2*>(out + (size_t)node * 64 + 4 * fl) = pk;
    }
}

// ---------------- pooling (batch is sorted: run-accumulate in registers) ----------------

__global__ void k_pool(const __half* __restrict__ h, const int* __restrict__ batch,
                       float* __restrict__ msum, float* __restrict__ mmax,
                       float* __restrict__ cnt) {
    int lane = threadIdx.x & 63;
    int wave = threadIdx.x >> 6;
    int start = blockIdx.x * 256 + wave * 64;
    if (start >= NN) return;
    int end = min(start + 64, NN);
    int cur = batch[start];
    float s = 0.0f, m = 0.0f;
    int run = 0;
    for (int n = start; n < end; n++) {
        int g = batch[n];
        if (g != cur) {
            atomicAdd(&msum[cur * 64 + lane], s);
            atomicMax((int*)&mmax[cur * 64 + lane], __float_as_int(m));
            if (lane == 0) atomicAdd(&cnt[cur], (float)run);
            s = 0.0f; m = 0.0f; run = 0; cur = g;
        }
        float v = __half2float(h[(size_t)n * 64 + lane]);
        s += v;
        m = fmaxf(m, v);
        run++;
    }
    atomicAdd(&msum[cur * 64 + lane], s);
    atomicMax((int*)&mmax[cur * 64 + lane], __float_as_int(m));
    if (lane == 0) atomicAdd(&cnt[cur], (float)run);
}

// ---------------- classifier head ----------------

__global__ void k_cls(const float* __restrict__ msum, const float* __restrict__ mmax,
                      const float* __restrict__ cnt,
                      const float* __restrict__ cw1, const float* __restrict__ cb1,
                      const float* __restrict__ g1,  const float* __restrict__ be1,
                      const float* __restrict__ cw2, const float* __restrict__ cb2,
                      const float* __restrict__ g2,  const float* __restrict__ be2,
                      const float* __restrict__ cw3, const float* __restrict__ cb3,
                      float* __restrict__ out) {
    __shared__ float emb[128];
    __shared__ float z1[64];
    __shared__ float z2[32];
    int g = blockIdx.x;
    int t = threadIdx.x;
    float invc = 1.0f / fmaxf(cnt[g], 1.0f);
    emb[t]      = msum[g * 64 + t] * invc;
    emb[64 + t] = mmax[g * 64 + t];
    __syncthreads();
    float acc = cb1[t];
#pragma unroll
    for (int k = 0; k < 128; k++) acc = fmaf(emb[k], cw1[k * 64 + t], acc);
    acc = acc * (g1[t] / sqrtf(1.0f + BN_EPS)) + be1[t];
    z1[t] = fmaxf(acc, 0.0f);
    __syncthreads();
    if (t < 32) {
        float a = cb2[t];
#pragma unroll
        for (int k = 0; k < 64; k++) a = fmaf(z1[k], cw2[k * 32 + t], a);
        a = a * (g2[t] / sqrtf(1.0f + BN_EPS)) + be2[t];
        z2[t] = fmaxf(a, 0.0f);
    }
    __syncthreads();
    if (t < 5) {
        float a = cb3[t];
#pragma unroll
        for (int k = 0; k < 32; k++) a = fmaf(z2[k], cw3[k * 5 + t], a);
        out[g * 5 + t] = a;
    }
}

// ---------------- launch ----------------

extern "C" void kernel_launch(void* const* d_in, const int* in_sizes, int n_in,
                              void* d_out, int out_size, void* d_ws, size_t ws_size,
                              hipStream_t stream) {
    const float* x     = (const float*)d_in[0];
    const int*   ei    = (const int*)d_in[1];
    const int*   src   = ei;
    const int*   dst   = ei + NE;
    const int*   batch = (const int*)d_in[2];
    const float* W1  = (const float*)d_in[3];
    const float* b1  = (const float*)d_in[4];
    const float* W2  = (const float*)d_in[5];
    const float* b2  = (const float*)d_in[6];
    const float* W3  = (const float*)d_in[7];
    const float* b3  = (const float*)d_in[8];
    const float* cw1 = (const float*)d_in[9];
    const float* cb1 = (const float*)d_in[10];
    const float* g1  = (const float*)d_in[11];
    const float* be1 = (const float*)d_in[12];
    const float* cw2 = (const float*)d_in[13];
    const float* cb2 = (const float*)d_in[14];
    const float* g2  = (const float*)d_in[15];
    const float* be2 = (const float*)d_in[16];
    const float* cw3 = (const float*)d_in[17];
    const float* cb3 = (const float*)d_in[18];
    float* out = (float*)d_out;

    char* ws = (char*)d_ws;
    size_t off = 0;
    auto alloc = [&](size_t bytes) {
        off = (off + 255) & ~(size_t)255;
        void* p = ws + off;
        off += bytes;
        return p;
    };

    int*    indeg    = (int*)alloc(NN * 4);
    float*  dinv     = (float*)alloc(NN * 4);
    int*    rowstart = (int*)alloc(NN * 4);
    int*    slot     = (int*)alloc((size_t)NE * 4);
    int*    bsum     = (int*)alloc(512 * 4);
    int2*   csr      = (int2*)alloc((size_t)NE * 8);
    __half* A        = (__half*)alloc((size_t)NN * 64 * 2);
    __half* B        = (__half*)alloc((size_t)NN * 64 * 2);
    float*  msum     = (float*)alloc((size_t)NG * 64 * 4);
    float*  mmax     = (float*)alloc((size_t)NG * 64 * 4);
    float*  cnt      = (float*)alloc((size_t)NG * 4);

    const int NB_E = (NE + 255) / 256;    // 4688
    const int NB_N = (NN + 255) / 256;    // 391

    k_init <<<256, 256, 0, stream>>>(indeg, msum, mmax, cnt);
    k_indeg<<<NB_E, 256, 0, stream>>>(dst, indeg, slot);
    k_scan1<<<NB_N, 256, 0, stream>>>(indeg, bsum, dinv);
    k_scan2<<<1, 512, 0, stream>>>(bsum, NB_N);
    k_scan3<<<NB_N, 256, 0, stream>>>(indeg, bsum, rowstart);
    k_fill <<<NB_E, 256, 0, stream>>>(src, dst, rowstart, slot, dinv, csr);

    const int NB_D = NN / 4;  // 25000

    // layer 1
    k_dense<IND, float><<<NB_D, 256, 0, stream>>>(x, W1, A);
    k_gather4e<<<NB_D, 256, 0, stream>>>(A, rowstart, indeg, csr, dinv, b1, B);
    // layer 2
    k_dense<HIDD, __half><<<NB_D, 256, 0, stream>>>(B, W2, A);
    k_gather4e<<<NB_D, 256, 0, stream>>>(A, rowstart, indeg, csr, dinv, b2, B);
    // layer 3
    k_dense<HIDD, __half><<<NB_D, 256, 0, stream>>>(B, W3, A);
    k_gather4e<<<NB_D, 256, 0, stream>>>(A, rowstart, indeg, csr, dinv, b3, B);

    k_pool<<<NB_N, 256, 0, stream>>>(B, batch, msum, mmax, cnt);

    k_cls<<<NG, 64, 0, stream>>>(msum, mmax, cnt, cw1, cb1, g1, be1,
                                 cw2, cb2, g2, be2, cw3, cb3, out);
}

// Round 10
// 336.416 us; speedup vs baseline: 1.4519x; 1.2298x over previous
//
#include <hip/hip_runtime.h>
#include <hip/hip_fp16.h>

#define NN 100000
#define NE 1200000
#define NG 2000
#define IND 36
#define HIDD 64
#define BN_EPS 1e-5f

typedef _Float16 half8 __attribute__((ext_vector_type(8)));
typedef float f32x4 __attribute__((ext_vector_type(4)));

// fma of 4 packed halves (one 8B register pair) into 4 f32 accumulators
__device__ __forceinline__ void fma4u(float& a0, float& a1, float& a2, float& a3,
                                      uint2 raw, float c) {
    __half2 u, v;
    *reinterpret_cast<unsigned*>(&u) = raw.x;
    *reinterpret_cast<unsigned*>(&v) = raw.y;
    float2 uf = __half22float2(u);
    float2 vf = __half22float2(v);
    a0 = fmaf(uf.x, c, a0);
    a1 = fmaf(uf.y, c, a1);
    a2 = fmaf(vf.x, c, a2);
    a3 = fmaf(vf.y, c, a3);
}

// ---------------- init: zero all accumulator buffers in one launch ----------------

__global__ void k_init(int* __restrict__ indeg, float* __restrict__ msum,
                       float* __restrict__ mmax, float* __restrict__ cnt) {
    int i = blockIdx.x * 256 + threadIdx.x;
    int stride = gridDim.x * 256;
    for (int j = i; j < NN; j += stride) indeg[j] = 0;
    for (int j = i; j < NG * 64; j += stride) { msum[j] = 0.0f; mmax[j] = 0.0f; }
    for (int j = i; j < NG; j += stride) cnt[j] = 0.0f;
}

// ---------------- CSR build ----------------

__global__ void k_indeg(const int* __restrict__ dst, int* __restrict__ indeg,
                        int* __restrict__ slot) {
    int e = blockIdx.x * 256 + threadIdx.x;
    if (e < NE) slot[e] = atomicAdd(&indeg[dst[e]], 1);
}

__global__ void k_scan1(const int* __restrict__ indeg, int* __restrict__ bsum,
                        float* __restrict__ dinv) {
    __shared__ int sh[256];
    int i = blockIdx.x * 256 + threadIdx.x;
    int v = (i < NN) ? indeg[i] : 0;
    if (i < NN) dinv[i] = rsqrtf((float)v + 1.0f);
    sh[threadIdx.x] = v;
    __syncthreads();
    for (int s = 128; s > 0; s >>= 1) {
        if (threadIdx.x < s) sh[threadIdx.x] += sh[threadIdx.x + s];
        __syncthreads();
    }
    if (threadIdx.x == 0) bsum[blockIdx.x] = sh[0];
}

__global__ void k_scan2(int* __restrict__ bsum, int nb) {
    __shared__ int sh[512];
    int t = threadIdx.x;
    int v = (t < nb) ? bsum[t] : 0;
    sh[t] = v;
    __syncthreads();
    for (int s = 1; s < 512; s <<= 1) {
        int u = (t >= s) ? sh[t - s] : 0;
        __syncthreads();
        sh[t] += u;
        __syncthreads();
    }
    if (t < nb) bsum[t] = sh[t] - v;  // exclusive
}

__global__ void k_scan3(const int* __restrict__ indeg, const int* __restrict__ bsum,
                        int* __restrict__ rowstart) {
    __shared__ int sh[256];
    int i = blockIdx.x * 256 + threadIdx.x;
    int v = (i < NN) ? indeg[i] : 0;
    sh[threadIdx.x] = v;
    __syncthreads();
    for (int s = 1; s < 256; s <<= 1) {
        int t = (threadIdx.x >= s) ? sh[threadIdx.x - s] : 0;
        __syncthreads();
        sh[threadIdx.x] += t;
        __syncthreads();
    }
    if (i < NN) rowstart[i] = bsum[blockIdx.x] + sh[threadIdx.x] - v;  // exclusive
}

__global__ void k_fill(const int* __restrict__ src, const int* __restrict__ dst,
                       const int* __restrict__ rowstart, const int* __restrict__ slot,
                       const float* __restrict__ dinv, int2* __restrict__ csr) {
    int e = blockIdx.x * 256 + threadIdx.x;
    if (e < NE) {
        int s = src[e], d = dst[e];
        int p = rowstart[d] + slot[e];
        int2 ent;
        ent.x = s;
        ent.y = __float_as_int(dinv[s] * dinv[d]);
        csr[p] = ent;
    }
}

// ---------------- weight prep: Wt[j][k] = W[k][j], fp16, W1 k-padded to 64 ----------------

__global__ void k_wprep(const float* __restrict__ W1, const float* __restrict__ W2,
                        const float* __restrict__ W3, __half* __restrict__ Wt1,
                        __half* __restrict__ Wt2, __half* __restrict__ Wt3) {
    int i = blockIdx.x * 256 + threadIdx.x;
    if (i < 64 * 64) {
        int j = i >> 6, k = i & 63;
        Wt1[i] = __float2half((k < IND) ? W1[k * 64 + j] : 0.0f);
        Wt2[i] = __float2half(W2[k * 64 + j]);
        Wt3[i] = __float2half(W3[k * 64 + j]);
    }
}

// ---------------- x convert: f32 [N,36] -> fp16 [N,64] zero-padded ----------------

__global__ void k_xcvt(const float* __restrict__ x, __half* __restrict__ xh) {
    int node = blockIdx.x * 4 + (threadIdx.x >> 6);
    int lane = threadIdx.x & 63;
    if (node < NN)
        xh[(size_t)node * 64 + lane] =
            __float2half((lane < IND) ? x[(size_t)node * IND + lane] : 0.0f);
}

// ---------------- MFMA dense: out[N,64] = Ah[N,64] @ W (via Wt), fp16 in/out, f32 acc ----------------
// Per wave: 16 nodes x 16 cols, K=64 as 2x mfma_f32_16x16x32_f16.
// A frag: lane l -> row l&15, k = (l>>4)*8 + e (contiguous half8 from row-major A).
// B frag: lane l -> col l&15, k = (l>>4)*8 + e (contiguous half8 from transposed Wt).
// C/D:    lane l -> col l&15, row = (l>>4)*4 + reg   [m89-verified]

__global__ void k_mdense(const __half* __restrict__ Ah, const __half* __restrict__ Wt,
                         __half* __restrict__ out) {
    int wv = threadIdx.x >> 6;   // wave -> col block
    int l  = threadIdx.x & 63;
    int r16 = l & 15;
    int kb  = (l >> 4) * 8;
    size_t n0 = (size_t)blockIdx.x * 16;

    half8 a0 = *reinterpret_cast<const half8*>(Ah + (n0 + r16) * 64 + kb);
    half8 a1 = *reinterpret_cast<const half8*>(Ah + (n0 + r16) * 64 + 32 + kb);
    int col = wv * 16 + r16;
    half8 b0 = *reinterpret_cast<const half8*>(Wt + (size_t)col * 64 + kb);
    half8 b1 = *reinterpret_cast<const half8*>(Wt + (size_t)col * 64 + 32 + kb);

    f32x4 acc = {0.0f, 0.0f, 0.0f, 0.0f};
    acc = __builtin_amdgcn_mfma_f32_16x16x32_f16(a0, b0, acc, 0, 0, 0);
    acc = __builtin_amdgcn_mfma_f32_16x16x32_f16(a1, b1, acc, 0, 0, 0);

    int orow = (l >> 4) * 4;
#pragma unroll
    for (int r = 0; r < 4; r++)
        out[(n0 + orow + r) * 64 + col] = __float2half(acc[r]);
}

// ---------------- gather: 4 edges per load instruction ----------------

__global__ void k_gather4e(const __half* __restrict__ hlin, const int* __restrict__ rowstart,
                           const int* __restrict__ indeg, const int2* __restrict__ csr,
                           const float* __restrict__ dinv, const float* __restrict__ bias,
                           __half* __restrict__ out) {
    int node = blockIdx.x * 4 + (threadIdx.x >> 6);
    int lane = threadIdx.x & 63;
    int sub  = (lane >> 4);
    int fl   = lane & 15;
    if (node >= NN) return;

    float di = dinv[node];
    float a0 = 0, a1 = 0, a2 = 0, a3 = 0;
    {   // self loop, counted only in sub==0
        uint2 sv = *reinterpret_cast<const uint2*>(hlin + (size_t)node * 64 + 4 * fl);
        float m = (sub == 0) ? di * di : 0.0f;
        fma4u(a0, a1, a2, a3, sv, m);
    }

    int start = rowstart[node];
    int len   = indeg[node];
    for (int k = 0; k < len; k += 8) {
        int i0 = k + sub;
        int i1 = k + 4 + sub;
        int2 e0 = (i0 < len) ? csr[start + i0] : make_int2(0, 0);
        int2 e1 = (i1 < len) ? csr[start + i1] : make_int2(0, 0);
        uint2 r0 = *reinterpret_cast<const uint2*>(hlin + (size_t)e0.x * 64 + 4 * fl);
        uint2 r1 = *reinterpret_cast<const uint2*>(hlin + (size_t)e1.x * 64 + 4 * fl);
        fma4u(a0, a1, a2, a3, r0, __int_as_float(e0.y));
        fma4u(a0, a1, a2, a3, r1, __int_as_float(e1.y));
    }

    a0 += __shfl_xor(a0, 16, 64);  a1 += __shfl_xor(a1, 16, 64);
    a2 += __shfl_xor(a2, 16, 64);  a3 += __shfl_xor(a3, 16, 64);
    a0 += __shfl_xor(a0, 32, 64);  a1 += __shfl_xor(a1, 32, 64);
    a2 += __shfl_xor(a2, 32, 64);  a3 += __shfl_xor(a3, 32, 64);

    if (sub == 0) {
        float4 b = *reinterpret_cast<const float4*>(bias + 4 * fl);
        float o0 = fmaxf(a0 + b.x, 0.0f);
        float o1 = fmaxf(a1 + b.y, 0.0f);
        float o2 = fmaxf(a2 + b.z, 0.0f);
        float o3 = fmaxf(a3 + b.w, 0.0f);
        __half2 p01 = __floats2half2_rn(o0, o1);
        __half2 p23 = __floats2half2_rn(o2, o3);
        uint2 pk;
        pk.x = *reinterpret_cast<unsigned*>(&p01);
        pk.y = *reinterpret_cast<unsigned*>(&p23);
        *reinterpret_cast<uint2*>(out + (size_t)node * 64 + 4 * fl) = pk;
    }
}

// ---------------- pooling (batch is sorted: run-accumulate in registers) ----------------

__global__ void k_pool(const __half* __restrict__ h, const int* __restrict__ batch,
                       float* __restrict__ msum, float* __restrict__ mmax,
                       float* __restrict__ cnt) {
    int lane = threadIdx.x & 63;
    int wave = threadIdx.x >> 6;
    int start = blockIdx.x * 256 + wave * 64;
    if (start >= NN) return;
    int end = min(start + 64, NN);
    int cur = batch[start];
    float s = 0.0f, m = 0.0f;
    int run = 0;
    for (int n = start; n < end; n++) {
        int g = batch[n];
        if (g != cur) {
            atomicAdd(&msum[cur * 64 + lane], s);
            atomicMax((int*)&mmax[cur * 64 + lane], __float_as_int(m));
            if (lane == 0) atomicAdd(&cnt[cur], (float)run);
            s = 0.0f; m = 0.0f; run = 0; cur = g;
        }
        float v = __half2float(h[(size_t)n * 64 + lane]);
        s += v;
        m = fmaxf(m, v);
        run++;
    }
    atomicAdd(&msum[cur * 64 + lane], s);
    atomicMax((int*)&mmax[cur * 64 + lane], __float_as_int(m));
    if (lane == 0) atomicAdd(&cnt[cur], (float)run);
}

// ---------------- classifier head ----------------

__global__ void k_cls(const float* __restrict__ msum, const float* __restrict__ mmax,
                      const float* __restrict__ cnt,
                      const float* __restrict__ cw1, const float* __restrict__ cb1,
                      const float* __restrict__ g1,  const float* __restrict__ be1,
                      const float* __restrict__ cw2, const float* __restrict__ cb2,
                      const float* __restrict__ g2,  const float* __restrict__ be2,
                      const float* __restrict__ cw3, const float* __restrict__ cb3,
                      float* __restrict__ out) {
    __shared__ float emb[128];
    __shared__ float z1[64];
    __shared__ float z2[32];
    int g = blockIdx.x;
    int t = threadIdx.x;
    float invc = 1.0f / fmaxf(cnt[g], 1.0f);
    emb[t]      = msum[g * 64 + t] * invc;
    emb[64 + t] = mmax[g * 64 + t];
    __syncthreads();
    float acc = cb1[t];
#pragma unroll
    for (int k = 0; k < 128; k++) acc = fmaf(emb[k], cw1[k * 64 + t], acc);
    acc = acc * (g1[t] / sqrtf(1.0f + BN_EPS)) + be1[t];
    z1[t] = fmaxf(acc, 0.0f);
    __syncthreads();
    if (t < 32) {
        float a = cb2[t];
#pragma unroll
        for (int k = 0; k < 64; k++) a = fmaf(z1[k], cw2[k * 32 + t], a);
        a = a * (g2[t] / sqrtf(1.0f + BN_EPS)) + be2[t];
        z2[t] = fmaxf(a, 0.0f);
    }
    __syncthreads();
    if (t < 5) {
        float a = cb3[t];
#pragma unroll
        for (int k = 0; k < 32; k++) a = fmaf(z2[k], cw3[k * 5 + t], a);
        out[g * 5 + t] = a;
    }
}

// ---------------- launch ----------------

extern "C" void kernel_launch(void* const* d_in, const int* in_sizes, int n_in,
                              void* d_out, int out_size, void* d_ws, size_t ws_size,
                              hipStream_t stream) {
    const float* x     = (const float*)d_in[0];
    const int*   ei    = (const int*)d_in[1];
    const int*   src   = ei;
    const int*   dst   = ei + NE;
    const int*   batch = (const int*)d_in[2];
    const float* W1  = (const float*)d_in[3];
    const float* b1  = (const float*)d_in[4];
    const float* W2  = (const float*)d_in[5];
    const float* b2  = (const float*)d_in[6];
    const float* W3  = (const float*)d_in[7];
    const float* b3  = (const float*)d_in[8];
    const float* cw1 = (const float*)d_in[9];
    const float* cb1 = (const float*)d_in[10];
    const float* g1  = (const float*)d_in[11];
    const float* be1 = (const float*)d_in[12];
    const float* cw2 = (const float*)d_in[13];
    const float* cb2 = (const float*)d_in[14];
    const float* g2  = (const float*)d_in[15];
    const float* be2 = (const float*)d_in[16];
    const float* cw3 = (const float*)d_in[17];
    const float* cb3 = (const float*)d_in[18];
    float* out = (float*)d_out;

    char* ws = (char*)d_ws;
    size_t off = 0;
    auto alloc = [&](size_t bytes) {
        off = (off + 255) & ~(size_t)255;
        void* p = ws + off;
        off += bytes;
        return p;
    };

    int*    indeg    = (int*)alloc(NN * 4);
    float*  dinv     = (float*)alloc(NN * 4);
    int*    rowstart = (int*)alloc(NN * 4);
    int*    slot     = (int*)alloc((size_t)NE * 4);
    int*    bsum     = (int*)alloc(512 * 4);
    int2*   csr      = (int2*)alloc((size_t)NE * 8);
    __half* A        = (__half*)alloc((size_t)NN * 64 * 2);
    __half* B        = (__half*)alloc((size_t)NN * 64 * 2);
    __half* xh       = (__half*)alloc((size_t)NN * 64 * 2);
    __half* Wt1      = (__half*)alloc(64 * 64 * 2);
    __half* Wt2      = (__half*)alloc(64 * 64 * 2);
    __half* Wt3      = (__half*)alloc(64 * 64 * 2);
    float*  msum     = (float*)alloc((size_t)NG * 64 * 4);
    float*  mmax     = (float*)alloc((size_t)NG * 64 * 4);
    float*  cnt      = (float*)alloc((size_t)NG * 4);

    const int NB_E = (NE + 255) / 256;    // 4688
    const int NB_N = (NN + 255) / 256;    // 391
    const int NB_D = NN / 4;              // 25000
    const int NB_M = NN / 16;             // 6250

    k_init <<<256, 256, 0, stream>>>(indeg, msum, mmax, cnt);
    k_wprep<<<16, 256, 0, stream>>>(W1, W2, W3, Wt1, Wt2, Wt3);
    k_xcvt <<<NB_D, 256, 0, stream>>>(x, xh);
    k_indeg<<<NB_E, 256, 0, stream>>>(dst, indeg, slot);
    k_scan1<<<NB_N, 256, 0, stream>>>(indeg, bsum, dinv);
    k_scan2<<<1, 512, 0, stream>>>(bsum, NB_N);
    k_scan3<<<NB_N, 256, 0, stream>>>(indeg, bsum, rowstart);
    k_fill <<<NB_E, 256, 0, stream>>>(src, dst, rowstart, slot, dinv, csr);

    // layer 1
    k_mdense<<<NB_M, 256, 0, stream>>>(xh, Wt1, A);
    k_gather4e<<<NB_D, 256, 0, stream>>>(A, rowstart, indeg, csr, dinv, b1, B);
    // layer 2
    k_mdense<<<NB_M, 256, 0, stream>>>(B, Wt2, A);
    k_gather4e<<<NB_D, 256, 0, stream>>>(A, rowstart, indeg, csr, dinv, b2, B);
    // layer 3
    k_mdense<<<NB_M, 256, 0, stream>>>(B, Wt3, A);
    k_gather4e<<<NB_D, 256, 0, stream>>>(A, rowstart, indeg, csr, dinv, b3, B);

    k_pool<<<NB_N, 256, 0, stream>>>(B, batch, msum, mmax, cnt);

    k_cls<<<NG, 64, 0, stream>>>(msum, mmax, cnt, cw1, cb1, g1, be1,
                                 cw2, cb2, g2, be2, cw3, cb3, out);
}